// Round 5
// baseline (206.123 us; speedup 1.0000x reference)
//
#include <hip/hip_runtime.h>
#include <hip/hip_bf16.h>
#include <math.h>

// MDAM, fully fused. Reference reduces to:
//   x_att = softmax(gn_b)                          (GN spatial mean == gn_b exactly)
//   y0[bg,o] = b3[o] + mean(conv3x3(x)[bg,o])      (from 9 scalars per (bg,i))
//   w[bg,c]  = sigmoid(x_att[c] + sigmoid(fc2 @ relu(fc1 @ y0))[c])
//   out      = input * w[bg,c]
// One block per group (256 blocks x 1024 threads, 16 waves = 1 wave/image).
// Phase 1: stats scan with 8-deep batched loads (latency hiding).
// Phase 2: weights in-LDS.
// Phase 3: reverse-order re-read (L3-resident from phase 1) + NT-stored scale.

#define CG 16
#define NGROUP 256
#define IMG_F4 4096          // 128*128/4 float4 per image
#define IMG_ELEMS 16384

typedef float f32x4 __attribute__((ext_vector_type(4)));

__global__ __launch_bounds__(1024) void mdam_fused(const f32x4* __restrict__ x,
                                                   const float* __restrict__ w3,
                                                   const float* __restrict__ b3,
                                                   const float* __restrict__ gn_b,
                                                   const float* __restrict__ fc1,
                                                   const float* __restrict__ fc2,
                                                   f32x4* __restrict__ out) {
    __shared__ float s_stats[CG][16];     // [img][stat]; 0=T 1=R0 2=RL 3=C0 4=CL 5..8=corners
    __shared__ float s_w3[CG * CG * 9];
    __shared__ float s_fc1[CG * CG], s_fc2[CG * CG];
    __shared__ float s_b3[CG], s_gnb[CG];
    __shared__ float s_y0[CG], s_t1[CG], s_wt[CG];

    const int g    = blockIdx.x;
    const int tid  = threadIdx.x;
    const int lane = tid & 63;
    const int wave = tid >> 6;            // 16 waves; wave w owns image w

    // preload small weights
    for (int k = tid; k < CG * CG * 9; k += 1024) s_w3[k] = w3[k];
    if (tid < CG * CG) { s_fc1[tid] = fc1[tid]; s_fc2[tid] = fc2[tid]; }
    if (tid < CG)      { s_b3[tid] = b3[tid];   s_gnb[tid] = gn_b[tid]; }

    const f32x4* xg = x + (size_t)g * CG * IMG_F4;
    const f32x4* p  = xg + (size_t)wave * IMG_F4;

    // ---------------- Phase 1: stats (forward scan, 8 batches x 8 loads) ----
    float t = 0.f, vx = 0.f, vw = 0.f, r0 = 0.f, rl = 0.f;
    for (int b = 0; b < 8; ++b) {
        f32x4 vv[8];
#pragma unroll
        for (int j = 0; j < 8; ++j) vv[j] = p[lane + (((b << 3) + j) << 6)];
#pragma unroll
        for (int j = 0; j < 8; ++j) {
            t  += vv[j].x + vv[j].y + vv[j].z + vv[j].w;
            vx += vv[j].x;
            vw += vv[j].w;
        }
        if (b == 0) {               // k==0 holds rows 0..1; row0 == lanes<32
            const float s4 = vv[0].x + vv[0].y + vv[0].z + vv[0].w;
            r0 = (lane < 32) ? s4 : 0.f;
            if (lane == 0)  s_stats[wave][5] = vv[0].x;   // x[0,0]
            if (lane == 31) s_stats[wave][6] = vv[0].w;   // x[0,127]
        }
        if (b == 7) {               // k==63 holds rows 126..127; row127 == lanes>=32
            const float s4 = vv[7].x + vv[7].y + vv[7].z + vv[7].w;
            rl = (lane >= 32) ? s4 : 0.f;
            if (lane == 32) s_stats[wave][7] = vv[7].x;   // x[127,0]
            if (lane == 63) s_stats[wave][8] = vv[7].w;   // x[127,127]
        }
    }
    const float c0 = ((lane & 31) == 0)  ? vx : 0.f;      // col 0
    const float cl = ((lane & 31) == 31) ? vw : 0.f;      // col 127

    float vals[5] = {t, r0, rl, c0, cl};
#pragma unroll
    for (int off = 32; off > 0; off >>= 1) {
#pragma unroll
        for (int j = 0; j < 5; ++j) vals[j] += __shfl_xor(vals[j], off);
    }
    if (lane == 0) {
#pragma unroll
        for (int j = 0; j < 5; ++j) s_stats[wave][j] = vals[j];
    }
    __syncthreads();

    // ---------------- Phase 2: weights ----------------
    if (tid < 256) {
        const int o = tid >> 4, i = tid & 15;
        const float* st = s_stats[i];
        const float T = st[0], R0 = st[1], RL = st[2], C0 = st[3], CL = st[4];
        const float x00 = st[5], x0L = st[6], xL0 = st[7], xLL = st[8];
        const float er[3]     = {RL, 0.f, R0};
        const float ec[3]     = {CL, 0.f, C0};
        const float cor[3][3] = {{xLL, 0.f, xL0},
                                 {0.f, 0.f, 0.f},
                                 {x0L, 0.f, x00}};
        const float* w = &s_w3[(o * CG + i) * 9];
        float part = 0.f;
#pragma unroll
        for (int dy = 0; dy < 3; ++dy)
#pragma unroll
            for (int dx = 0; dx < 3; ++dx)
                part += w[dy * 3 + dx] * (T - er[dy] - ec[dx] + cor[dy][dx]);
        part += __shfl_xor(part, 1);
        part += __shfl_xor(part, 2);
        part += __shfl_xor(part, 4);
        part += __shfl_xor(part, 8);
        if (i == 0) s_y0[o] = s_b3[o] + part * (1.0f / (float)IMG_ELEMS);
    }
    __syncthreads();
    if (tid < CG) {
        float a1 = 0.f;
#pragma unroll
        for (int i = 0; i < CG; ++i) a1 += s_fc1[tid * CG + i] * s_y0[i];
        s_t1[tid] = fmaxf(a1, 0.f);
    }
    __syncthreads();
    if (tid < CG) {
        float a2 = 0.f;
#pragma unroll
        for (int i = 0; i < CG; ++i) a2 += s_fc2[tid * CG + i] * s_t1[i];
        const float ybr = 1.f / (1.f + expf(-a2));
        float m = s_gnb[0];
#pragma unroll
        for (int i = 1; i < CG; ++i) m = fmaxf(m, s_gnb[i]);
        float den = 0.f;
#pragma unroll
        for (int i = 0; i < CG; ++i) den += expf(s_gnb[i] - m);
        const float xatt = expf(s_gnb[tid] - m) / den;
        s_wt[tid] = 1.f / (1.f + expf(-(xatt + ybr)));
    }
    __syncthreads();

    // ---------------- Phase 3: apply (reverse scan, batched, NT stores) -----
    const float wgt = s_wt[wave];
    f32x4* o = out + (size_t)g * CG * IMG_F4 + (size_t)wave * IMG_F4;
    for (int b = 7; b >= 0; --b) {
        f32x4 vv[8];
#pragma unroll
        for (int j = 0; j < 8; ++j) vv[j] = p[lane + (((b << 3) + j) << 6)];
#pragma unroll
        for (int j = 0; j < 8; ++j)
            __builtin_nontemporal_store(vv[j] * wgt, &o[lane + (((b << 3) + j) << 6)]);
    }
}

extern "C" void kernel_launch(void* const* d_in, const int* in_sizes, int n_in,
                              void* d_out, int out_size, void* d_ws, size_t ws_size,
                              hipStream_t stream) {
    const float* x    = (const float*)d_in[0];
    const float* w3   = (const float*)d_in[3];
    const float* b3   = (const float*)d_in[4];
    const float* gn_b = (const float*)d_in[6];
    const float* fc1  = (const float*)d_in[7];
    const float* fc2  = (const float*)d_in[8];

    mdam_fused<<<NGROUP, 1024, 0, stream>>>(
        reinterpret_cast<const f32x4*>(x), w3, b3, gn_b, fc1, fc2,
        reinterpret_cast<f32x4*>(d_out));
}

// Round 6
// 120.757 us; speedup vs baseline: 1.7069x; 1.7069x over previous
//
#include <hip/hip_runtime.h>
#include <hip/hip_bf16.h>
#include <math.h>

// MDAM, fully fused. Reference reduces to:
//   x_att = softmax(gn_b)                          (GN spatial mean == gn_b exactly)
//   y0[bg,o] = b3[o] + mean(conv3x3(x)[bg,o])      (from 9 scalars per (bg,i))
//   w[bg,c]  = sigmoid(x_att[c] + sigmoid(fc2 @ relu(fc1 @ y0))[c])
//   out      = input * w[bg,c]
// One block per group (256 blocks x 512 threads, 8 waves; wave owns images
// 2w, 2w+1). R4 structure (proven traffic: FETCH~255MiB, WRITE~262MiB);
// phase 1 now interleaves the wave's two image streams with 4-deep batches
// (8 independent loads in flight) to fix the latency-bound read phase.
// Phase 3 keeps the reverse interleaved load->NT-store rhythm, 2 streams.

#define CG 16
#define NGROUP 256
#define IMG_F4 4096          // 128*128/4 float4 per image
#define IMG_ELEMS 16384

typedef float f32x4 __attribute__((ext_vector_type(4)));

__global__ __launch_bounds__(512) void mdam_fused(const f32x4* __restrict__ x,
                                                  const float* __restrict__ w3,
                                                  const float* __restrict__ b3,
                                                  const float* __restrict__ gn_b,
                                                  const float* __restrict__ fc1,
                                                  const float* __restrict__ fc2,
                                                  f32x4* __restrict__ out) {
    __shared__ float s_stats[CG][16];     // [img][stat]; 0=T 1=R0 2=RL 3=C0 4=CL 5..8=corners
    __shared__ float s_w3[CG * CG * 9];
    __shared__ float s_fc1[CG * CG], s_fc2[CG * CG];
    __shared__ float s_b3[CG], s_gnb[CG];
    __shared__ float s_y0[CG], s_t1[CG], s_wt[CG];

    const int g    = blockIdx.x;
    const int tid  = threadIdx.x;
    const int lane = tid & 63;
    const int wave = tid >> 6;            // 8 waves; wave owns images 2w, 2w+1

    // preload small weights
    for (int k = tid; k < CG * CG * 9; k += 512) s_w3[k] = w3[k];
    if (tid < CG * CG) { s_fc1[tid] = fc1[tid]; s_fc2[tid] = fc2[tid]; }
    if (tid < CG)      { s_b3[tid] = b3[tid];   s_gnb[tid] = gn_b[tid]; }

    const int imgA = wave * 2, imgB = wave * 2 + 1;
    const f32x4* xg = x + (size_t)g * CG * IMG_F4;
    const f32x4* pA = xg + (size_t)imgA * IMG_F4;
    const f32x4* pB = xg + (size_t)imgB * IMG_F4;

    // ---------------- Phase 1: stats (forward, 2 streams x 4-deep) ----------
    float tA = 0.f, vxA = 0.f, vwA = 0.f, r0A = 0.f, rlA = 0.f;
    float tB = 0.f, vxB = 0.f, vwB = 0.f, r0B = 0.f, rlB = 0.f;
    for (int b = 0; b < 16; ++b) {
        f32x4 va[4], vb[4];
#pragma unroll
        for (int j = 0; j < 4; ++j) {
            const int k = (b << 2) + j;
            va[j] = pA[lane + (k << 6)];
            vb[j] = pB[lane + (k << 6)];
        }
#pragma unroll
        for (int j = 0; j < 4; ++j) {
            tA  += va[j].x + va[j].y + va[j].z + va[j].w;
            vxA += va[j].x;  vwA += va[j].w;
            tB  += vb[j].x + vb[j].y + vb[j].z + vb[j].w;
            vxB += vb[j].x;  vwB += vb[j].w;
        }
        if (b == 0) {   // k==0 holds rows 0..1; row0 == lanes<32
            const float sA = va[0].x + va[0].y + va[0].z + va[0].w;
            const float sB = vb[0].x + vb[0].y + vb[0].z + vb[0].w;
            r0A = (lane < 32) ? sA : 0.f;
            r0B = (lane < 32) ? sB : 0.f;
            if (lane == 0)  { s_stats[imgA][5] = va[0].x; s_stats[imgB][5] = vb[0].x; }
            if (lane == 31) { s_stats[imgA][6] = va[0].w; s_stats[imgB][6] = vb[0].w; }
        }
        if (b == 15) {  // k==63 holds rows 126..127; row127 == lanes>=32
            const float sA = va[3].x + va[3].y + va[3].z + va[3].w;
            const float sB = vb[3].x + vb[3].y + vb[3].z + vb[3].w;
            rlA = (lane >= 32) ? sA : 0.f;
            rlB = (lane >= 32) ? sB : 0.f;
            if (lane == 32) { s_stats[imgA][7] = va[3].x; s_stats[imgB][7] = vb[3].x; }
            if (lane == 63) { s_stats[imgA][8] = va[3].w; s_stats[imgB][8] = vb[3].w; }
        }
    }
    const float c0A = ((lane & 31) == 0)  ? vxA : 0.f;
    const float clA = ((lane & 31) == 31) ? vwA : 0.f;
    const float c0B = ((lane & 31) == 0)  ? vxB : 0.f;
    const float clB = ((lane & 31) == 31) ? vwB : 0.f;

    float vals[10] = {tA, r0A, rlA, c0A, clA, tB, r0B, rlB, c0B, clB};
#pragma unroll
    for (int off = 32; off > 0; off >>= 1) {
#pragma unroll
        for (int j = 0; j < 10; ++j) vals[j] += __shfl_xor(vals[j], off);
    }
    if (lane == 0) {
#pragma unroll
        for (int j = 0; j < 5; ++j) {
            s_stats[imgA][j] = vals[j];
            s_stats[imgB][j] = vals[5 + j];
        }
    }
    __syncthreads();

    // ---------------- Phase 2: weights ----------------
    if (tid < 256) {
        const int o = tid >> 4, i = tid & 15;
        const float* st = s_stats[i];
        const float T = st[0], R0 = st[1], RL = st[2], C0 = st[3], CL = st[4];
        const float x00 = st[5], x0L = st[6], xL0 = st[7], xLL = st[8];
        const float er[3]     = {RL, 0.f, R0};
        const float ec[3]     = {CL, 0.f, C0};
        const float cor[3][3] = {{xLL, 0.f, xL0},
                                 {0.f, 0.f, 0.f},
                                 {x0L, 0.f, x00}};
        const float* w = &s_w3[(o * CG + i) * 9];
        float part = 0.f;
#pragma unroll
        for (int dy = 0; dy < 3; ++dy)
#pragma unroll
            for (int dx = 0; dx < 3; ++dx)
                part += w[dy * 3 + dx] * (T - er[dy] - ec[dx] + cor[dy][dx]);
        part += __shfl_xor(part, 1);
        part += __shfl_xor(part, 2);
        part += __shfl_xor(part, 4);
        part += __shfl_xor(part, 8);
        if (i == 0) s_y0[o] = s_b3[o] + part * (1.0f / (float)IMG_ELEMS);
    }
    __syncthreads();
    if (tid < CG) {
        float a1 = 0.f;
#pragma unroll
        for (int i = 0; i < CG; ++i) a1 += s_fc1[tid * CG + i] * s_y0[i];
        s_t1[tid] = fmaxf(a1, 0.f);
    }
    __syncthreads();
    if (tid < CG) {
        float a2 = 0.f;
#pragma unroll
        for (int i = 0; i < CG; ++i) a2 += s_fc2[tid * CG + i] * s_t1[i];
        const float ybr = 1.f / (1.f + expf(-a2));
        float m = s_gnb[0];
#pragma unroll
        for (int i = 1; i < CG; ++i) m = fmaxf(m, s_gnb[i]);
        float den = 0.f;
#pragma unroll
        for (int i = 0; i < CG; ++i) den += expf(s_gnb[i] - m);
        const float xatt = expf(s_gnb[tid] - m) / den;
        s_wt[tid] = 1.f / (1.f + expf(-(xatt + ybr)));
    }
    __syncthreads();

    // ---------------- Phase 3: apply (reverse scan, 2 streams, NT stores) ---
    const float wA = s_wt[imgA], wB = s_wt[imgB];
    f32x4* og = out + (size_t)g * CG * IMG_F4;
    f32x4* oA = og + (size_t)imgA * IMG_F4;
    f32x4* oB = og + (size_t)imgB * IMG_F4;
    for (int k = 63; k >= 0; --k) {
        const int idx = lane + (k << 6);
        f32x4 va = pA[idx];
        f32x4 vb = pB[idx];
        __builtin_nontemporal_store(va * wA, &oA[idx]);
        __builtin_nontemporal_store(vb * wB, &oB[idx]);
    }
}

extern "C" void kernel_launch(void* const* d_in, const int* in_sizes, int n_in,
                              void* d_out, int out_size, void* d_ws, size_t ws_size,
                              hipStream_t stream) {
    const float* x    = (const float*)d_in[0];
    const float* w3   = (const float*)d_in[3];
    const float* b3   = (const float*)d_in[4];
    const float* gn_b = (const float*)d_in[6];
    const float* fc1  = (const float*)d_in[7];
    const float* fc2  = (const float*)d_in[8];

    mdam_fused<<<NGROUP, 512, 0, stream>>>(
        reinterpret_cast<const f32x4*>(x), w3, b3, gn_b, fc1, fc2,
        reinterpret_cast<f32x4*>(d_out));
}

// Round 7
// 119.302 us; speedup vs baseline: 1.7277x; 1.0122x over previous
//
#include <hip/hip_runtime.h>
#include <hip/hip_bf16.h>
#include <math.h>

// MDAM, fully fused. Reference reduces to:
//   x_att = softmax(gn_b)                          (GN spatial mean == gn_b exactly)
//   y0[bg,o] = b3[o] + mean(conv3x3(x)[bg,o])      (from 9 scalars per (bg,i))
//   w[bg,c]  = sigmoid(x_att[c] + sigmoid(fc2 @ relu(fc1 @ y0))[c])
//   out      = input * w[bg,c]
// One block per group (256 blocks x 512 threads, 8 waves; wave owns images
// 2w, 2w+1). Proven traffic: FETCH~255MiB (phase-3 reads are L3 hits),
// WRITE~262MiB. This round: phase 3 is software-pipelined 2 iterations deep
// so stores wait only on loads issued 2 iterations ago (counted vmcnt), and
// prior stores never gate the next loads.

#define CG 16
#define NGROUP 256
#define IMG_F4 4096          // 128*128/4 float4 per image
#define IMG_ELEMS 16384

typedef float f32x4 __attribute__((ext_vector_type(4)));

__global__ __launch_bounds__(512) void mdam_fused(const f32x4* __restrict__ x,
                                                  const float* __restrict__ w3,
                                                  const float* __restrict__ b3,
                                                  const float* __restrict__ gn_b,
                                                  const float* __restrict__ fc1,
                                                  const float* __restrict__ fc2,
                                                  f32x4* __restrict__ out) {
    __shared__ float s_stats[CG][16];     // [img][stat]; 0=T 1=R0 2=RL 3=C0 4=CL 5..8=corners
    __shared__ float s_w3[CG * CG * 9];
    __shared__ float s_fc1[CG * CG], s_fc2[CG * CG];
    __shared__ float s_b3[CG], s_gnb[CG];
    __shared__ float s_y0[CG], s_t1[CG], s_wt[CG];

    const int g    = blockIdx.x;
    const int tid  = threadIdx.x;
    const int lane = tid & 63;
    const int wave = tid >> 6;            // 8 waves; wave owns images 2w, 2w+1

    // preload small weights
    for (int k = tid; k < CG * CG * 9; k += 512) s_w3[k] = w3[k];
    if (tid < CG * CG) { s_fc1[tid] = fc1[tid]; s_fc2[tid] = fc2[tid]; }
    if (tid < CG)      { s_b3[tid] = b3[tid];   s_gnb[tid] = gn_b[tid]; }

    const int imgA = wave * 2, imgB = wave * 2 + 1;
    const f32x4* xg = x + (size_t)g * CG * IMG_F4;
    const f32x4* pA = xg + (size_t)imgA * IMG_F4;
    const f32x4* pB = xg + (size_t)imgB * IMG_F4;

    // ---------------- Phase 1: stats (forward, 2 streams x 4-deep) ----------
    float tA = 0.f, vxA = 0.f, vwA = 0.f, r0A = 0.f, rlA = 0.f;
    float tB = 0.f, vxB = 0.f, vwB = 0.f, r0B = 0.f, rlB = 0.f;
    for (int b = 0; b < 16; ++b) {
        f32x4 va[4], vb[4];
#pragma unroll
        for (int j = 0; j < 4; ++j) {
            const int k = (b << 2) + j;
            va[j] = pA[lane + (k << 6)];
            vb[j] = pB[lane + (k << 6)];
        }
#pragma unroll
        for (int j = 0; j < 4; ++j) {
            tA  += va[j].x + va[j].y + va[j].z + va[j].w;
            vxA += va[j].x;  vwA += va[j].w;
            tB  += vb[j].x + vb[j].y + vb[j].z + vb[j].w;
            vxB += vb[j].x;  vwB += vb[j].w;
        }
        if (b == 0) {   // k==0 holds rows 0..1; row0 == lanes<32
            const float sA = va[0].x + va[0].y + va[0].z + va[0].w;
            const float sB = vb[0].x + vb[0].y + vb[0].z + vb[0].w;
            r0A = (lane < 32) ? sA : 0.f;
            r0B = (lane < 32) ? sB : 0.f;
            if (lane == 0)  { s_stats[imgA][5] = va[0].x; s_stats[imgB][5] = vb[0].x; }
            if (lane == 31) { s_stats[imgA][6] = va[0].w; s_stats[imgB][6] = vb[0].w; }
        }
        if (b == 15) {  // k==63 holds rows 126..127; row127 == lanes>=32
            const float sA = va[3].x + va[3].y + va[3].z + va[3].w;
            const float sB = vb[3].x + vb[3].y + vb[3].z + vb[3].w;
            rlA = (lane >= 32) ? sA : 0.f;
            rlB = (lane >= 32) ? sB : 0.f;
            if (lane == 32) { s_stats[imgA][7] = va[3].x; s_stats[imgB][7] = vb[3].x; }
            if (lane == 63) { s_stats[imgA][8] = va[3].w; s_stats[imgB][8] = vb[3].w; }
        }
    }
    const float c0A = ((lane & 31) == 0)  ? vxA : 0.f;
    const float clA = ((lane & 31) == 31) ? vwA : 0.f;
    const float c0B = ((lane & 31) == 0)  ? vxB : 0.f;
    const float clB = ((lane & 31) == 31) ? vwB : 0.f;

    float vals[10] = {tA, r0A, rlA, c0A, clA, tB, r0B, rlB, c0B, clB};
#pragma unroll
    for (int off = 32; off > 0; off >>= 1) {
#pragma unroll
        for (int j = 0; j < 10; ++j) vals[j] += __shfl_xor(vals[j], off);
    }
    if (lane == 0) {
#pragma unroll
        for (int j = 0; j < 5; ++j) {
            s_stats[imgA][j] = vals[j];
            s_stats[imgB][j] = vals[5 + j];
        }
    }
    __syncthreads();

    // ---------------- Phase 2: weights ----------------
    if (tid < 256) {
        const int o = tid >> 4, i = tid & 15;
        const float* st = s_stats[i];
        const float T = st[0], R0 = st[1], RL = st[2], C0 = st[3], CL = st[4];
        const float x00 = st[5], x0L = st[6], xL0 = st[7], xLL = st[8];
        const float er[3]     = {RL, 0.f, R0};
        const float ec[3]     = {CL, 0.f, C0};
        const float cor[3][3] = {{xLL, 0.f, xL0},
                                 {0.f, 0.f, 0.f},
                                 {x0L, 0.f, x00}};
        const float* w = &s_w3[(o * CG + i) * 9];
        float part = 0.f;
#pragma unroll
        for (int dy = 0; dy < 3; ++dy)
#pragma unroll
            for (int dx = 0; dx < 3; ++dx)
                part += w[dy * 3 + dx] * (T - er[dy] - ec[dx] + cor[dy][dx]);
        part += __shfl_xor(part, 1);
        part += __shfl_xor(part, 2);
        part += __shfl_xor(part, 4);
        part += __shfl_xor(part, 8);
        if (i == 0) s_y0[o] = s_b3[o] + part * (1.0f / (float)IMG_ELEMS);
    }
    __syncthreads();
    if (tid < CG) {
        float a1 = 0.f;
#pragma unroll
        for (int i = 0; i < CG; ++i) a1 += s_fc1[tid * CG + i] * s_y0[i];
        s_t1[tid] = fmaxf(a1, 0.f);
    }
    __syncthreads();
    if (tid < CG) {
        float a2 = 0.f;
#pragma unroll
        for (int i = 0; i < CG; ++i) a2 += s_fc2[tid * CG + i] * s_t1[i];
        const float ybr = 1.f / (1.f + expf(-a2));
        float m = s_gnb[0];
#pragma unroll
        for (int i = 1; i < CG; ++i) m = fmaxf(m, s_gnb[i]);
        float den = 0.f;
#pragma unroll
        for (int i = 0; i < CG; ++i) den += expf(s_gnb[i] - m);
        const float xatt = expf(s_gnb[tid] - m) / den;
        s_wt[tid] = 1.f / (1.f + expf(-(xatt + ybr)));
    }
    __syncthreads();

    // ---- Phase 3: apply (reverse scan, 2-deep SW pipeline, NT stores) ------
    // Stores consume data loaded TWO iterations earlier; each iteration issues
    // next loads BEFORE its stores, so waits are counted-vmcnt on old loads
    // and outstanding stores never gate the read stream.
    const float wA = s_wt[imgA], wB = s_wt[imgB];
    f32x4* og = out + (size_t)g * CG * IMG_F4;
    f32x4* oA = og + (size_t)imgA * IMG_F4;
    f32x4* oB = og + (size_t)imgB * IMG_F4;

    f32x4 a0 = pA[lane + (63 << 6)], b0 = pB[lane + (63 << 6)];
    f32x4 a1 = pA[lane + (62 << 6)], b1 = pB[lane + (62 << 6)];
    for (int k = 63; k >= 2; --k) {
        const f32x4 na = pA[lane + ((k - 2) << 6)];   // issue loads first
        const f32x4 nb = pB[lane + ((k - 2) << 6)];
        __builtin_nontemporal_store(a0 * wA, &oA[lane + (k << 6)]);
        __builtin_nontemporal_store(b0 * wB, &oB[lane + (k << 6)]);
        a0 = a1; b0 = b1;
        a1 = na; b1 = nb;
    }
    __builtin_nontemporal_store(a0 * wA, &oA[lane + (1 << 6)]);
    __builtin_nontemporal_store(b0 * wB, &oB[lane + (1 << 6)]);
    __builtin_nontemporal_store(a1 * wA, &oA[lane]);
    __builtin_nontemporal_store(b1 * wB, &oB[lane]);
}

extern "C" void kernel_launch(void* const* d_in, const int* in_sizes, int n_in,
                              void* d_out, int out_size, void* d_ws, size_t ws_size,
                              hipStream_t stream) {
    const float* x    = (const float*)d_in[0];
    const float* w3   = (const float*)d_in[3];
    const float* b3   = (const float*)d_in[4];
    const float* gn_b = (const float*)d_in[6];
    const float* fc1  = (const float*)d_in[7];
    const float* fc2  = (const float*)d_in[8];

    mdam_fused<<<NGROUP, 512, 0, stream>>>(
        reinterpret_cast<const f32x4*>(x), w3, b3, gn_b, fc1, fc2,
        reinterpret_cast<f32x4*>(d_out));
}